// Round 6
// baseline (192.431 us; speedup 1.0000x reference)
//
#include <hip/hip_runtime.h>

#define NB 8
#define SD 512
#define HW 128
#define EPS 1e-5f

__device__ __forceinline__ int refl(int r) { return r < 0 ? 1 : (r > 127 ? 126 : r); }

// ============ prep: [0,2048) inorm stats | [2048,2064) style mean | [2064,4112) gen_dw
__global__ __launch_bounds__(256) void prep_k(const float* __restrict__ pred,
                                              const float* __restrict__ style,
                                              const float* __restrict__ dww,
                                              const float* __restrict__ dwb,
                                              float* __restrict__ s_ws,
                                              float* __restrict__ dw_ws,
                                              float* __restrict__ mean_ws,
                                              float* __restrict__ inv_ws) {
    __shared__ float ws4[4], wss4[4];
    int b = blockIdx.x, t = threadIdx.x;
    if (b < 2048) {
        // ---- instance-norm stats: block per (n,c) ----
        const float4* p = (const float4*)(pred + (size_t)b * HW * HW);
        float s = 0.f, ss = 0.f;
#pragma unroll
        for (int k = 0; k < 16; ++k) {
            float4 v = p[k * 256 + t];
            s  += v.x + v.y + v.z + v.w;
            ss += v.x * v.x + v.y * v.y + v.z * v.z + v.w * v.w;
        }
#pragma unroll
        for (int off = 32; off; off >>= 1) {
            s  += __shfl_down(s, off);
            ss += __shfl_down(ss, off);
        }
        if ((t & 63) == 0) { ws4[t >> 6] = s; wss4[t >> 6] = ss; }
        __syncthreads();
        if (t == 0) {
            float S  = ws4[0] + ws4[1] + ws4[2] + ws4[3];
            float SS = wss4[0] + wss4[1] + wss4[2] + wss4[3];
            float m = S * (1.f / (HW * HW));
            float var = SS * (1.f / (HW * HW)) - m * m;
            mean_ws[b] = m;
            inv_ws[b] = rsqrtf(var + EPS);
        }
    } else if (b < 2064) {
        // ---- style spatial mean ----
        int u = (b - 2048) * 256 + t;
        const float* p = style + (size_t)u * 16;
        float a = 0.f;
#pragma unroll
        for (int k = 0; k < 16; ++k) a += p[k];
        s_ws[u] = a * (1.f / 16.f);
    } else {
        // ---- dw kernel generation: wave per f, 4 f per block sharing style ----
        int bb = b - 2064;               // n fastest -> dww L2 reuse
        int n = bb & 7;
        int f = ((bb >> 3) << 2) + (t >> 6);
        int lane = t & 63;
        float acc[9];
#pragma unroll
        for (int k = 0; k < 9; ++k) acc[k] = 0.f;
#pragma unroll 2
        for (int it = 0; it < 8; ++it) {
            int c = lane + (it << 6);
            const float4* sp = (const float4*)(style + ((size_t)n * SD + c) * 16);
            float st[16];
#pragma unroll
            for (int k = 0; k < 4; ++k) {
                float4 v = sp[k];
                st[k * 4 + 0] = v.x; st[k * 4 + 1] = v.y;
                st[k * 4 + 2] = v.z; st[k * 4 + 3] = v.w;
            }
            float4 w = *(const float4*)(dww + ((size_t)f * SD + c) * 4);
#pragma unroll
            for (int p = 0; p < 3; ++p)
#pragma unroll
                for (int q = 0; q < 3; ++q)
                    acc[p * 3 + q] += st[p * 4 + q] * w.x + st[p * 4 + q + 1] * w.y
                                    + st[(p + 1) * 4 + q] * w.z + st[(p + 1) * 4 + q + 1] * w.w;
        }
#pragma unroll
        for (int k = 0; k < 9; ++k)
#pragma unroll
            for (int off = 32; off; off >>= 1) acc[k] += __shfl_down(acc[k], off);
        if (lane == 0) {
            float bias = dwb[f];
#pragma unroll
            for (int k = 0; k < 9; ++k)
                dw_ws[((size_t)n * 1024 + f) * 9 + k] = acc[k] + bias;
        }
    }
}

// ============ pointwise kernels + bias: one wave per output, coalesced ================
__global__ __launch_bounds__(256) void gen_pw_k(const float* __restrict__ s_ws,
                                                const float* __restrict__ pkw,
                                                const float* __restrict__ pkb,
                                                const float* __restrict__ pbw,
                                                const float* __restrict__ pbb,
                                                float* __restrict__ pwk,
                                                float* __restrict__ pwbias) {
    int w = blockIdx.x * 4 + (threadIdx.x >> 6);   // 0..10239
    int lane = threadIdx.x & 63;
    int n = w / 1280;
    int j = w - n * 1280;
    bool isk = j < 1024;
    const float2* wrow = (const float2*)(isk ? (pkw + (size_t)j * SD)
                                             : (pbw + (size_t)(j - 1024) * SD));
    const float2* s2 = (const float2*)(s_ws + (size_t)n * SD);
    float a = 0.f;
#pragma unroll
    for (int it = 0; it < 4; ++it) {
        int c2 = lane + (it << 6);
        float2 x = s2[c2];
        float2 v = wrow[c2];
        a += x.x * v.x + x.y * v.y;
    }
#pragma unroll
    for (int off = 32; off; off >>= 1) a += __shfl_down(a, off);
    if (lane == 0) {
        if (isk) pwk[(size_t)n * 1024 + j] = a + pkb[j];
        else     pwbias[(size_t)n * 256 + (j - 1024)] = a + pbb[j - 1024];
    }
}

// ============ fold: W[ic][kh][kw][o] = inv[ic]*sum_i pwk[o,i]*dw[i,ic,kh,kw] ==========
//              B[o] = pwbias[o] - sum_i pwk[o,i] * sum_ic m*inv * sum_k dw[i,ic,k]
__global__ __launch_bounds__(192) void fold_k(float* __restrict__ dw_ws,
                                              const float* __restrict__ pwk_ws,
                                              float* __restrict__ pwb_ws,
                                              const float* __restrict__ mean_ws,
                                              const float* __restrict__ inv_ws) {
    __shared__ float dwl[144], pwkl[16], invl[4], msc[4], pwbl[4];
    int b = blockIdx.x;              // n*64+g
    int n = b >> 6, g = b & 63;
    int t = threadIdx.x;
    size_t dbase = (size_t)(n * 1024 + g * 16) * 9;     // == (n*64+g)*144
    if (t < 144) dwl[t] = dw_ws[dbase + t];
    else if (t < 160) pwkl[t - 144] = pwk_ws[(size_t)n * 1024 + g * 16 + (t - 144)];
    else if (t < 164) {
        int ic = t - 160;
        float m = mean_ws[n * 256 + g * 4 + ic];
        float s = inv_ws[n * 256 + g * 4 + ic];
        invl[ic] = s; msc[ic] = m * s;
    } else if (t < 168) {
        pwbl[t - 164] = pwb_ws[n * 256 + g * 4 + (t - 164)];
    }
    __syncthreads();
    if (t < 144) {
        int o = t / 36, rm = t % 36, ic = rm / 9, k = rm % 9;
        int kh = k / 3, kw = k % 3;
        float a = 0.f;
#pragma unroll
        for (int i = 0; i < 4; ++i) a += pwkl[o * 4 + i] * dwl[(i * 4 + ic) * 9 + k];
        // transposed layout for main: [ic][kh][kw][o]
        dw_ws[dbase + (size_t)(((ic * 3 + kh) * 3 + kw) * 4 + o)] = a * invl[ic];
    } else if (t < 148) {
        int o = t - 144;
        float cb = 0.f;
#pragma unroll
        for (int i = 0; i < 4; ++i) {
            float s2 = 0.f;
#pragma unroll
            for (int ic = 0; ic < 4; ++ic) {
                float sk = 0.f;
#pragma unroll
                for (int k = 0; k < 9; ++k) sk += dwl[(i * 4 + ic) * 9 + k];
                s2 += msc[ic] * sk;
            }
            cb += pwkl[o * 4 + i] * s2;
        }
        pwb_ws[n * 256 + g * 4 + o] = pwbl[o] - cb;
    }
}

// ============ fused main: register-window streaming stencil ===========================
// 128-thr block (2 waves) covers (n,g) x 32 rows. Lane: cols 4*(l&31), 8 rows.
// Rotating 3-row x 4-ch float4 window; next-row loads issued before kh=0,1 compute.
// Horizontal halo via __shfl(+-1); column reflect = own .y/.z. No LDS tile, no barrier
// in the row loop.
__global__ __launch_bounds__(128) void adaconv_main_k(const float* __restrict__ pred,
                                                      const float* __restrict__ Wf,
                                                      const float* __restrict__ Bf,
                                                      float* __restrict__ out) {
    __shared__ float wf[148];
    int b = blockIdx.x;              // 2048 = 4stripe * 64g * 8n (stripe fastest)
    int stripe = b & 3;
    int g = (b >> 2) & 63;
    int n = b >> 8;
    int t = threadIdx.x;
    const size_t gbase = (size_t)(n * 64 + g);
    for (int i = t; i < 144; i += 128) wf[i] = Wf[gbase * 144 + i];
    if (t < 4) wf[144 + t] = Bf[gbase * 4 + t];
    __syncthreads();

    int l = t & 63, wv = t >> 6;
    int lr = l & 31, half = l >> 5;
    int r0 = (stripe << 5) + (wv << 4) + (half << 3);    // first output row (0..120)
    const size_t cbase = (size_t)(n * 256 + g * 4);
    const float* pc0 = pred + cbase * (HW * HW) + (lr << 2);
    float* oc0 = out + cbase * (HW * HW) + (lr << 2);

    float4 win[4][3];
#pragma unroll
    for (int ic = 0; ic < 4; ++ic) {
        win[ic][0] = *(const float4*)(pc0 + ic * (HW * HW) + refl(r0 - 1) * HW);
        win[ic][1] = *(const float4*)(pc0 + ic * (HW * HW) + r0 * HW);
    }
    float b0 = wf[144], b1 = wf[145], b2 = wf[146], b3 = wf[147];

#pragma unroll
    for (int k = 0; k < 8; ++k) {
        // issue next-row loads (land in slot (k+2)%3, consumed at kh=2)
#pragma unroll
        for (int ic = 0; ic < 4; ++ic)
            win[ic][(k + 2) % 3] = *(const float4*)(pc0 + ic * (HW * HW) + refl(r0 + k + 1) * HW);

        float acc[4][4];
#pragma unroll
        for (int p = 0; p < 4; ++p) {
            acc[0][p] = b0; acc[1][p] = b1; acc[2][p] = b2; acc[3][p] = b3;
        }

#pragma unroll
        for (int kh = 0; kh < 3; ++kh) {            // kh=2 uses the freshly loaded row
#pragma unroll
            for (int ic = 0; ic < 4; ++ic) {
                float4 v = win[ic][(k + kh) % 3];
                float lv = __shfl(v.w, l - 1);
                float rv = __shfl(v.x, l + 1);
                lv = (lr == 0) ? v.y : lv;          // reflect col -1 -> col 1
                rv = (lr == 31) ? v.z : rv;         // reflect col 128 -> col 126
                float e[6] = {lv, v.x, v.y, v.z, v.w, rv};
                const float* wp = &wf[(ic * 3 + kh) * 12];
#pragma unroll
                for (int kw = 0; kw < 3; ++kw) {
                    float4 wk = *(const float4*)(wp + kw * 4);   // 4 oc for this tap
#pragma unroll
                    for (int p = 0; p < 4; ++p) {
                        acc[0][p] = fmaf(wk.x, e[p + kw], acc[0][p]);
                        acc[1][p] = fmaf(wk.y, e[p + kw], acc[1][p]);
                        acc[2][p] = fmaf(wk.z, e[p + kw], acc[2][p]);
                        acc[3][p] = fmaf(wk.w, e[p + kw], acc[3][p]);
                    }
                }
            }
        }

        int r = r0 + k;
#pragma unroll
        for (int o = 0; o < 4; ++o)
            *(float4*)(oc0 + o * (HW * HW) + r * HW) =
                make_float4(acc[o][0], acc[o][1], acc[o][2], acc[o][3]);
    }
}

extern "C" void kernel_launch(void* const* d_in, const int* in_sizes, int n_in,
                              void* d_out, int out_size, void* d_ws, size_t ws_size,
                              hipStream_t stream) {
    const float* style = (const float*)d_in[0];   // [8,512,4,4]
    const float* pred  = (const float*)d_in[1];   // [8,256,128,128]
    const float* dww   = (const float*)d_in[2];   // [1024,512,2,2]
    const float* dwb   = (const float*)d_in[3];   // [1024]
    const float* pkw   = (const float*)d_in[4];   // [1024,512]
    const float* pkb   = (const float*)d_in[5];   // [1024]
    const float* pbw   = (const float*)d_in[6];   // [256,512]
    const float* pbb   = (const float*)d_in[7];   // [256]
    float* out = (float*)d_out;

    float* ws      = (float*)d_ws;
    float* s_ws    = ws;            // 4096
    float* dw_ws   = ws + 4096;     // 73728 (raw dw kernels, folded+transposed in place)
    float* pwk_ws  = ws + 77824;    // 8192
    float* pwb_ws  = ws + 86016;    // 2048 (folded bias in place)
    float* mean_ws = ws + 88064;    // 2048
    float* inv_ws  = ws + 90112;    // 2048  (end: 92160 floats)

    prep_k<<<4112, 256, 0, stream>>>(pred, style, dww, dwb, s_ws, dw_ws, mean_ws, inv_ws);
    gen_pw_k<<<2560, 256, 0, stream>>>(s_ws, pkw, pkb, pbw, pbb, pwk_ws, pwb_ws);
    fold_k<<<NB * 64, 192, 0, stream>>>(dw_ws, pwk_ws, pwb_ws, mean_ws, inv_ws);
    adaconv_main_k<<<2048, 128, 0, stream>>>(pred, dw_ws, pwb_ws, out);
}

// Round 7
// 110.273 us; speedup vs baseline: 1.7450x; 1.7450x over previous
//
#include <hip/hip_runtime.h>

#define NB 8
#define SD 512
#define HW 128
#define EPS 1e-5f

__device__ __forceinline__ int refl(int r) { return r < 0 ? 1 : (r > 127 ? 126 : r); }

__device__ __forceinline__ void async_copy16(const float* g, float* l) {
    __builtin_amdgcn_global_load_lds(
        (const __attribute__((address_space(1))) void*)g,
        (__attribute__((address_space(3))) void*)l, 16, 0, 0);
}

// ============ prep: [0,2048) inorm stats | [2048,2064) style mean | [2064,4112) gen_dw
__global__ __launch_bounds__(256) void prep_k(const float* __restrict__ pred,
                                              const float* __restrict__ style,
                                              const float* __restrict__ dww,
                                              const float* __restrict__ dwb,
                                              float* __restrict__ s_ws,
                                              float* __restrict__ dw_ws,
                                              float* __restrict__ mean_ws,
                                              float* __restrict__ inv_ws) {
    __shared__ float ws4[4], wss4[4];
    int b = blockIdx.x, t = threadIdx.x;
    if (b < 2048) {
        // ---- instance-norm stats: block per (n,c) ----
        const float4* p = (const float4*)(pred + (size_t)b * HW * HW);
        float s = 0.f, ss = 0.f;
#pragma unroll
        for (int k = 0; k < 16; ++k) {
            float4 v = p[k * 256 + t];
            s  += v.x + v.y + v.z + v.w;
            ss += v.x * v.x + v.y * v.y + v.z * v.z + v.w * v.w;
        }
#pragma unroll
        for (int off = 32; off; off >>= 1) {
            s  += __shfl_down(s, off);
            ss += __shfl_down(ss, off);
        }
        if ((t & 63) == 0) { ws4[t >> 6] = s; wss4[t >> 6] = ss; }
        __syncthreads();
        if (t == 0) {
            float S  = ws4[0] + ws4[1] + ws4[2] + ws4[3];
            float SS = wss4[0] + wss4[1] + wss4[2] + wss4[3];
            float m = S * (1.f / (HW * HW));
            float var = SS * (1.f / (HW * HW)) - m * m;
            mean_ws[b] = m;
            inv_ws[b] = rsqrtf(var + EPS);
        }
    } else if (b < 2064) {
        // ---- style spatial mean ----
        int u = (b - 2048) * 256 + t;
        const float* p = style + (size_t)u * 16;
        float a = 0.f;
#pragma unroll
        for (int k = 0; k < 16; ++k) a += p[k];
        s_ws[u] = a * (1.f / 16.f);
    } else {
        // ---- dw kernel generation: wave per f, 4 f per block sharing style ----
        int bb = b - 2064;               // n fastest -> dww L2 reuse
        int n = bb & 7;
        int f = ((bb >> 3) << 2) + (t >> 6);
        int lane = t & 63;
        float acc[9];
#pragma unroll
        for (int k = 0; k < 9; ++k) acc[k] = 0.f;
#pragma unroll 2
        for (int it = 0; it < 8; ++it) {
            int c = lane + (it << 6);
            const float4* sp = (const float4*)(style + ((size_t)n * SD + c) * 16);
            float st[16];
#pragma unroll
            for (int k = 0; k < 4; ++k) {
                float4 v = sp[k];
                st[k * 4 + 0] = v.x; st[k * 4 + 1] = v.y;
                st[k * 4 + 2] = v.z; st[k * 4 + 3] = v.w;
            }
            float4 w = *(const float4*)(dww + ((size_t)f * SD + c) * 4);
#pragma unroll
            for (int p = 0; p < 3; ++p)
#pragma unroll
                for (int q = 0; q < 3; ++q)
                    acc[p * 3 + q] += st[p * 4 + q] * w.x + st[p * 4 + q + 1] * w.y
                                    + st[(p + 1) * 4 + q] * w.z + st[(p + 1) * 4 + q + 1] * w.w;
        }
#pragma unroll
        for (int k = 0; k < 9; ++k)
#pragma unroll
            for (int off = 32; off; off >>= 1) acc[k] += __shfl_down(acc[k], off);
        if (lane == 0) {
            float bias = dwb[f];
#pragma unroll
            for (int k = 0; k < 9; ++k)
                dw_ws[((size_t)n * 1024 + f) * 9 + k] = acc[k] + bias;
        }
    }
}

// ============ pointwise kernels + bias: one wave per output, coalesced ================
__global__ __launch_bounds__(256) void gen_pw_k(const float* __restrict__ s_ws,
                                                const float* __restrict__ pkw,
                                                const float* __restrict__ pkb,
                                                const float* __restrict__ pbw,
                                                const float* __restrict__ pbb,
                                                float* __restrict__ pwk,
                                                float* __restrict__ pwbias) {
    int w = blockIdx.x * 4 + (threadIdx.x >> 6);   // 0..10239
    int lane = threadIdx.x & 63;
    int n = w / 1280;
    int j = w - n * 1280;
    bool isk = j < 1024;
    const float2* wrow = (const float2*)(isk ? (pkw + (size_t)j * SD)
                                             : (pbw + (size_t)(j - 1024) * SD));
    const float2* s2 = (const float2*)(s_ws + (size_t)n * SD);
    float a = 0.f;
#pragma unroll
    for (int it = 0; it < 4; ++it) {
        int c2 = lane + (it << 6);
        float2 x = s2[c2];
        float2 v = wrow[c2];
        a += x.x * v.x + x.y * v.y;
    }
#pragma unroll
    for (int off = 32; off; off >>= 1) a += __shfl_down(a, off);
    if (lane == 0) {
        if (isk) pwk[(size_t)n * 1024 + j] = a + pkb[j];
        else     pwbias[(size_t)n * 256 + (j - 1024)] = a + pbb[j - 1024];
    }
}

// ============ fold: W[ic][kh][kw][o] = inv[ic]*sum_i pwk[o,i]*dw[i,ic,kh,kw] ==========
//              B[o] = pwbias[o] - sum_i pwk[o,i] * sum_ic m*inv * sum_k dw[i,ic,k]
__global__ __launch_bounds__(192) void fold_k(float* __restrict__ dw_ws,
                                              const float* __restrict__ pwk_ws,
                                              float* __restrict__ pwb_ws,
                                              const float* __restrict__ mean_ws,
                                              const float* __restrict__ inv_ws) {
    __shared__ float dwl[144], pwkl[16], invl[4], msc[4], pwbl[4];
    int b = blockIdx.x;              // n*64+g
    int n = b >> 6, g = b & 63;
    int t = threadIdx.x;
    size_t dbase = (size_t)(n * 1024 + g * 16) * 9;     // == (n*64+g)*144
    if (t < 144) dwl[t] = dw_ws[dbase + t];
    else if (t < 160) pwkl[t - 144] = pwk_ws[(size_t)n * 1024 + g * 16 + (t - 144)];
    else if (t < 164) {
        int ic = t - 160;
        float m = mean_ws[n * 256 + g * 4 + ic];
        float s = inv_ws[n * 256 + g * 4 + ic];
        invl[ic] = s; msc[ic] = m * s;
    } else if (t < 168) {
        pwbl[t - 164] = pwb_ws[n * 256 + g * 4 + (t - 164)];
    }
    __syncthreads();
    if (t < 144) {
        int o = t / 36, rm = t % 36, ic = rm / 9, k = rm % 9;
        int kh = k / 3, kw = k % 3;
        float a = 0.f;
#pragma unroll
        for (int i = 0; i < 4; ++i) a += pwkl[o * 4 + i] * dwl[(i * 4 + ic) * 9 + k];
        // transposed layout for main: [ic][kh][kw][o]
        dw_ws[dbase + (size_t)(((ic * 3 + kh) * 3 + kw) * 4 + o)] = a * invl[ic];
    } else if (t < 148) {
        int o = t - 144;
        float cb = 0.f;
#pragma unroll
        for (int i = 0; i < 4; ++i) {
            float s2 = 0.f;
#pragma unroll
            for (int ic = 0; ic < 4; ++ic) {
                float sk = 0.f;
#pragma unroll
                for (int k = 0; k < 9; ++k) sk += dwl[(i * 4 + ic) * 9 + k];
                s2 += msc[ic] * sk;
            }
            cb += pwkl[o * 4 + i] * s2;
        }
        pwb_ws[n * 256 + g * 4 + o] = pwbl[o] - cb;
    }
}

// ============ fused main: full-width row strips, global_load_lds staging ==============
// Block = (n, g, 8-row strip) x 128 cols. Tile [4][10][128] staged via 20 direct
// global->LDS copies (wave wv stages channel wv). No column halo (reflect resolved
// from staged row). One barrier. Strip index fastest -> adjacent blocks share rows.
__global__ __launch_bounds__(256) void adaconv_main_k(const float* __restrict__ pred,
                                                      const float* __restrict__ Wf,
                                                      const float* __restrict__ Bf,
                                                      float* __restrict__ out) {
    __shared__ float tile[4][10][128];
    __shared__ float wf[148];
    int b = blockIdx.x;              // 8192 = 16strip * 64g * 8n (strip fastest)
    int strip = b & 15;
    int g = (b >> 4) & 63;
    int n = b >> 10;
    int t = threadIdx.x;
    const size_t gbase = (size_t)(n * 64 + g);
    const size_t cbase = (size_t)(n * 256 + g * 4);
    int r0 = strip << 3;

    // tile -> LDS: wave wv stages channel wv, 5 row-pairs of 128 cols each.
    // dest = uniform base + lane*16 (linear); src per-lane with row reflect.
    {
        int wv = t >> 6, l = t & 63;
        const float* pc = pred + (cbase + wv) * (HW * HW) + ((l & 31) << 2);
        int rhalf = l >> 5;
#pragma unroll
        for (int rp = 0; rp < 5; ++rp) {
            int rr = refl(r0 - 1 + rp * 2 + rhalf);
            async_copy16(pc + rr * HW, &tile[wv][rp * 2][0]);
        }
    }

    // weights + bias -> LDS
    if (t < 144) wf[t] = Wf[gbase * 144 + t];
    else if (t < 148) wf[t] = Bf[gbase * 4 + (t - 144)];

    __syncthreads();

    int row = t >> 5;                // 0..7 -> out row r0+row
    int colq = t & 31;               // cols 4*colq .. +3
    float acc[4][4];
#pragma unroll
    for (int o = 0; o < 4; ++o) {
        float bb = wf[144 + o];
#pragma unroll
        for (int p = 0; p < 4; ++p) acc[o][p] = bb;
    }

#pragma unroll
    for (int ic = 0; ic < 4; ++ic) {
#pragma unroll
        for (int kh = 0; kh < 3; ++kh) {
            const float* rp_ = &tile[ic][row + kh][0];
            float4 v = *(const float4*)(rp_ + (colq << 2));
            float lv = rp_[colq == 0 ? 1 : (colq << 2) - 1];    // col -1 -> col 1
            float rv = rp_[colq == 31 ? 126 : (colq << 2) + 4]; // col 128 -> col 126
            float e[6] = {lv, v.x, v.y, v.z, v.w, rv};
            const float* wp = &wf[(ic * 3 + kh) * 12];
#pragma unroll
            for (int kw = 0; kw < 3; ++kw) {
                float4 wk = *(const float4*)(wp + kw * 4);      // 4 oc at this tap
#pragma unroll
                for (int p = 0; p < 4; ++p) {
                    acc[0][p] = fmaf(wk.x, e[p + kw], acc[0][p]);
                    acc[1][p] = fmaf(wk.y, e[p + kw], acc[1][p]);
                    acc[2][p] = fmaf(wk.z, e[p + kw], acc[2][p]);
                    acc[3][p] = fmaf(wk.w, e[p + kw], acc[3][p]);
                }
            }
        }
    }

#pragma unroll
    for (int o = 0; o < 4; ++o) {
        *(float4*)(out + (cbase + o) * (HW * HW) + (size_t)(r0 + row) * HW + (colq << 2)) =
            make_float4(acc[o][0], acc[o][1], acc[o][2], acc[o][3]);
    }
}

extern "C" void kernel_launch(void* const* d_in, const int* in_sizes, int n_in,
                              void* d_out, int out_size, void* d_ws, size_t ws_size,
                              hipStream_t stream) {
    const float* style = (const float*)d_in[0];   // [8,512,4,4]
    const float* pred  = (const float*)d_in[1];   // [8,256,128,128]
    const float* dww   = (const float*)d_in[2];   // [1024,512,2,2]
    const float* dwb   = (const float*)d_in[3];   // [1024]
    const float* pkw   = (const float*)d_in[4];   // [1024,512]
    const float* pkb   = (const float*)d_in[5];   // [1024]
    const float* pbw   = (const float*)d_in[6];   // [256,512]
    const float* pbb   = (const float*)d_in[7];   // [256]
    float* out = (float*)d_out;

    float* ws      = (float*)d_ws;
    float* s_ws    = ws;            // 4096
    float* dw_ws   = ws + 4096;     // 73728 (raw dw kernels, folded+transposed in place)
    float* pwk_ws  = ws + 77824;    // 8192
    float* pwb_ws  = ws + 86016;    // 2048 (folded bias in place)
    float* mean_ws = ws + 88064;    // 2048
    float* inv_ws  = ws + 90112;    // 2048  (end: 92160 floats)

    prep_k<<<4112, 256, 0, stream>>>(pred, style, dww, dwb, s_ws, dw_ws, mean_ws, inv_ws);
    gen_pw_k<<<2560, 256, 0, stream>>>(s_ws, pkw, pkb, pbw, pbb, pwk_ws, pwb_ws);
    fold_k<<<NB * 64, 192, 0, stream>>>(dw_ws, pwk_ws, pwb_ws, mean_ws, inv_ws);
    adaconv_main_k<<<8192, 256, 0, stream>>>(pred, dw_ws, pwb_ws, out);
}

// Round 8
// 102.687 us; speedup vs baseline: 1.8740x; 1.0739x over previous
//
#include <hip/hip_runtime.h>

#define NB 8
#define SD 512
#define HW 128
#define EPS 1e-5f

__device__ __forceinline__ int refl(int r) { return r < 0 ? 1 : (r > 127 ? 126 : r); }

__device__ __forceinline__ void async_copy16(const float* g, float* l) {
    __builtin_amdgcn_global_load_lds(
        (const __attribute__((address_space(1))) void*)g,
        (__attribute__((address_space(3))) void*)l, 16, 0, 0);
}

// ============ prep: [0,2048) inorm stats | [2048,2064) style mean | [2064,4112) gen_dw
__global__ __launch_bounds__(256) void prep_k(const float* __restrict__ pred,
                                              const float* __restrict__ style,
                                              const float* __restrict__ dww,
                                              const float* __restrict__ dwb,
                                              float* __restrict__ s_ws,
                                              float* __restrict__ dw_ws,
                                              float* __restrict__ mean_ws,
                                              float* __restrict__ inv_ws) {
    __shared__ float ws4[4], wss4[4];
    int b = blockIdx.x, t = threadIdx.x;
    if (b < 2048) {
        // ---- instance-norm stats: block per (n,c) ----
        const float4* p = (const float4*)(pred + (size_t)b * HW * HW);
        float s = 0.f, ss = 0.f;
#pragma unroll
        for (int k = 0; k < 16; ++k) {
            float4 v = p[k * 256 + t];
            s  += v.x + v.y + v.z + v.w;
            ss += v.x * v.x + v.y * v.y + v.z * v.z + v.w * v.w;
        }
#pragma unroll
        for (int off = 32; off; off >>= 1) {
            s  += __shfl_down(s, off);
            ss += __shfl_down(ss, off);
        }
        if ((t & 63) == 0) { ws4[t >> 6] = s; wss4[t >> 6] = ss; }
        __syncthreads();
        if (t == 0) {
            float S  = ws4[0] + ws4[1] + ws4[2] + ws4[3];
            float SS = wss4[0] + wss4[1] + wss4[2] + wss4[3];
            float m = S * (1.f / (HW * HW));
            float var = SS * (1.f / (HW * HW)) - m * m;
            mean_ws[b] = m;
            inv_ws[b] = rsqrtf(var + EPS);
        }
    } else if (b < 2064) {
        // ---- style spatial mean ----
        int u = (b - 2048) * 256 + t;
        const float* p = style + (size_t)u * 16;
        float a = 0.f;
#pragma unroll
        for (int k = 0; k < 16; ++k) a += p[k];
        s_ws[u] = a * (1.f / 16.f);
    } else {
        // ---- dw kernel generation: wave per f, 4 f per block sharing style ----
        int bb = b - 2064;               // n fastest -> dww L2 reuse
        int n = bb & 7;
        int f = ((bb >> 3) << 2) + (t >> 6);
        int lane = t & 63;
        float acc[9];
#pragma unroll
        for (int k = 0; k < 9; ++k) acc[k] = 0.f;
#pragma unroll 2
        for (int it = 0; it < 8; ++it) {
            int c = lane + (it << 6);
            const float4* sp = (const float4*)(style + ((size_t)n * SD + c) * 16);
            float st[16];
#pragma unroll
            for (int k = 0; k < 4; ++k) {
                float4 v = sp[k];
                st[k * 4 + 0] = v.x; st[k * 4 + 1] = v.y;
                st[k * 4 + 2] = v.z; st[k * 4 + 3] = v.w;
            }
            float4 w = *(const float4*)(dww + ((size_t)f * SD + c) * 4);
#pragma unroll
            for (int p = 0; p < 3; ++p)
#pragma unroll
                for (int q = 0; q < 3; ++q)
                    acc[p * 3 + q] += st[p * 4 + q] * w.x + st[p * 4 + q + 1] * w.y
                                    + st[(p + 1) * 4 + q] * w.z + st[(p + 1) * 4 + q + 1] * w.w;
        }
#pragma unroll
        for (int k = 0; k < 9; ++k)
#pragma unroll
            for (int off = 32; off; off >>= 1) acc[k] += __shfl_down(acc[k], off);
        if (lane == 0) {
            float bias = dwb[f];
#pragma unroll
            for (int k = 0; k < 9; ++k)
                dw_ws[((size_t)n * 1024 + f) * 9 + k] = acc[k] + bias;
        }
    }
}

// ============ pointwise kernels + bias: one wave per output, coalesced ================
__global__ __launch_bounds__(256) void gen_pw_k(const float* __restrict__ s_ws,
                                                const float* __restrict__ pkw,
                                                const float* __restrict__ pkb,
                                                const float* __restrict__ pbw,
                                                const float* __restrict__ pbb,
                                                float* __restrict__ pwk,
                                                float* __restrict__ pwbias) {
    int w = blockIdx.x * 4 + (threadIdx.x >> 6);   // 0..10239
    int lane = threadIdx.x & 63;
    int n = w / 1280;
    int j = w - n * 1280;
    bool isk = j < 1024;
    const float2* wrow = (const float2*)(isk ? (pkw + (size_t)j * SD)
                                             : (pbw + (size_t)(j - 1024) * SD));
    const float2* s2 = (const float2*)(s_ws + (size_t)n * SD);
    float a = 0.f;
#pragma unroll
    for (int it = 0; it < 4; ++it) {
        int c2 = lane + (it << 6);
        float2 x = s2[c2];
        float2 v = wrow[c2];
        a += x.x * v.x + x.y * v.y;
    }
#pragma unroll
    for (int off = 32; off; off >>= 1) a += __shfl_down(a, off);
    if (lane == 0) {
        if (isk) pwk[(size_t)n * 1024 + j] = a + pkb[j];
        else     pwbias[(size_t)n * 256 + (j - 1024)] = a + pbb[j - 1024];
    }
}

// ============ fold: W[ic][kh][kw][o] = inv[ic]*sum_i pwk[o,i]*dw[i,ic,kh,kw] ==========
//              B[o] = pwbias[o] - sum_i pwk[o,i] * sum_ic m*inv * sum_k dw[i,ic,k]
__global__ __launch_bounds__(192) void fold_k(float* __restrict__ dw_ws,
                                              const float* __restrict__ pwk_ws,
                                              float* __restrict__ pwb_ws,
                                              const float* __restrict__ mean_ws,
                                              const float* __restrict__ inv_ws) {
    __shared__ float dwl[144], pwkl[16], invl[4], msc[4], pwbl[4];
    int b = blockIdx.x;              // n*64+g
    int n = b >> 6, g = b & 63;
    int t = threadIdx.x;
    size_t dbase = (size_t)(n * 1024 + g * 16) * 9;     // == (n*64+g)*144
    if (t < 144) dwl[t] = dw_ws[dbase + t];
    else if (t < 160) pwkl[t - 144] = pwk_ws[(size_t)n * 1024 + g * 16 + (t - 144)];
    else if (t < 164) {
        int ic = t - 160;
        float m = mean_ws[n * 256 + g * 4 + ic];
        float s = inv_ws[n * 256 + g * 4 + ic];
        invl[ic] = s; msc[ic] = m * s;
    } else if (t < 168) {
        pwbl[t - 164] = pwb_ws[n * 256 + g * 4 + (t - 164)];
    }
    __syncthreads();
    if (t < 144) {
        int o = t / 36, rm = t % 36, ic = rm / 9, k = rm % 9;
        int kh = k / 3, kw = k % 3;
        float a = 0.f;
#pragma unroll
        for (int i = 0; i < 4; ++i) a += pwkl[o * 4 + i] * dwl[(i * 4 + ic) * 9 + k];
        // transposed layout for main: [ic][kh][kw][o]
        dw_ws[dbase + (size_t)(((ic * 3 + kh) * 3 + kw) * 4 + o)] = a * invl[ic];
    } else if (t < 148) {
        int o = t - 144;
        float cb = 0.f;
#pragma unroll
        for (int i = 0; i < 4; ++i) {
            float s2 = 0.f;
#pragma unroll
            for (int ic = 0; ic < 4; ++ic) {
                float sk = 0.f;
#pragma unroll
                for (int k = 0; k < 9; ++k) sk += dwl[(i * 4 + ic) * 9 + k];
                s2 += msc[ic] * sk;
            }
            cb += pwkl[o * 4 + i] * s2;
        }
        pwb_ws[n * 256 + g * 4 + o] = pwbl[o] - cb;
    }
}

// ============ fused main: full-width row strips, global_load_lds staging ==============
// Block = (n, g, 8-row strip) x 128 cols. Tile [4][10][128] staged via 20 direct
// global->LDS copies. Halo columns resolved via aligned neighbor-quad float4 reads
// (+select for reflection) -- no scalar LDS reads, no bank conflicts.
__global__ __launch_bounds__(256) void adaconv_main_k(const float* __restrict__ pred,
                                                      const float* __restrict__ Wf,
                                                      const float* __restrict__ Bf,
                                                      float* __restrict__ out) {
    __shared__ float tile[4][10][128];
    __shared__ float wf[148];
    int b = blockIdx.x;              // 8192 = 16strip * 64g * 8n (strip fastest)
    int strip = b & 15;
    int g = (b >> 4) & 63;
    int n = b >> 10;
    int t = threadIdx.x;
    const size_t gbase = (size_t)(n * 64 + g);
    const size_t cbase = (size_t)(n * 256 + g * 4);
    int r0 = strip << 3;

    // tile -> LDS: wave wv stages channel wv, 5 row-pairs of 128 cols each.
    // dest = uniform base + lane*16 (linear); src per-lane with row reflect.
    {
        int wv = t >> 6, l = t & 63;
        const float* pc = pred + (cbase + wv) * (HW * HW) + ((l & 31) << 2);
        int rhalf = l >> 5;
#pragma unroll
        for (int rp = 0; rp < 5; ++rp) {
            int rr = refl(r0 - 1 + rp * 2 + rhalf);
            async_copy16(pc + rr * HW, &tile[wv][rp * 2][0]);
        }
    }

    // weights + bias -> LDS
    if (t < 144) wf[t] = Wf[gbase * 144 + t];
    else if (t < 148) wf[t] = Bf[gbase * 4 + (t - 144)];

    __syncthreads();

    int row = t >> 5;                // 0..7 -> out row r0+row
    int colq = t & 31;               // cols 4*colq .. +3
    int qL = colq == 0 ? 0 : colq - 1;
    int qR = colq == 31 ? 31 : colq + 1;
    float acc[4][4];
#pragma unroll
    for (int o = 0; o < 4; ++o) {
        float bb = wf[144 + o];
#pragma unroll
        for (int p = 0; p < 4; ++p) acc[o][p] = bb;
    }

#pragma unroll
    for (int ic = 0; ic < 4; ++ic) {
#pragma unroll
        for (int kh = 0; kh < 3; ++kh) {
            const float4* rq = (const float4*)&tile[ic][row + kh][0];
            float4 v  = rq[colq];
            float4 vL = rq[qL];
            float4 vR = rq[qR];
            float e0 = (colq == 0)  ? v.y : vL.w;   // reflect col -1 -> col 1
            float e5 = (colq == 31) ? v.z : vR.x;   // reflect col 128 -> col 126
            float e[6] = {e0, v.x, v.y, v.z, v.w, e5};
            const float* wp = &wf[(ic * 3 + kh) * 12];
#pragma unroll
            for (int kw = 0; kw < 3; ++kw) {
                float4 wk = *(const float4*)(wp + kw * 4);      // 4 oc at this tap
#pragma unroll
                for (int p = 0; p < 4; ++p) {
                    acc[0][p] = fmaf(wk.x, e[p + kw], acc[0][p]);
                    acc[1][p] = fmaf(wk.y, e[p + kw], acc[1][p]);
                    acc[2][p] = fmaf(wk.z, e[p + kw], acc[2][p]);
                    acc[3][p] = fmaf(wk.w, e[p + kw], acc[3][p]);
                }
            }
        }
    }

#pragma unroll
    for (int o = 0; o < 4; ++o) {
        *(float4*)(out + (cbase + o) * (HW * HW) + (size_t)(r0 + row) * HW + (colq << 2)) =
            make_float4(acc[o][0], acc[o][1], acc[o][2], acc[o][3]);
    }
}

extern "C" void kernel_launch(void* const* d_in, const int* in_sizes, int n_in,
                              void* d_out, int out_size, void* d_ws, size_t ws_size,
                              hipStream_t stream) {
    const float* style = (const float*)d_in[0];   // [8,512,4,4]
    const float* pred  = (const float*)d_in[1];   // [8,256,128,128]
    const float* dww   = (const float*)d_in[2];   // [1024,512,2,2]
    const float* dwb   = (const float*)d_in[3];   // [1024]
    const float* pkw   = (const float*)d_in[4];   // [1024,512]
    const float* pkb   = (const float*)d_in[5];   // [1024]
    const float* pbw   = (const float*)d_in[6];   // [256,512]
    const float* pbb   = (const float*)d_in[7];   // [256]
    float* out = (float*)d_out;

    float* ws      = (float*)d_ws;
    float* s_ws    = ws;            // 4096
    float* dw_ws   = ws + 4096;     // 73728 (raw dw kernels, folded+transposed in place)
    float* pwk_ws  = ws + 77824;    // 8192
    float* pwb_ws  = ws + 86016;    // 2048 (folded bias in place)
    float* mean_ws = ws + 88064;    // 2048
    float* inv_ws  = ws + 90112;    // 2048  (end: 92160 floats)

    prep_k<<<4112, 256, 0, stream>>>(pred, style, dww, dwb, s_ws, dw_ws, mean_ws, inv_ws);
    gen_pw_k<<<2560, 256, 0, stream>>>(s_ws, pkw, pkb, pbw, pbb, pwk_ws, pwb_ws);
    fold_k<<<NB * 64, 192, 0, stream>>>(dw_ws, pwk_ws, pwb_ws, mean_ws, inv_ws);
    adaconv_main_k<<<8192, 256, 0, stream>>>(pred, dw_ws, pwb_ws, out);
}